// Round 1
// baseline (808.455 us; speedup 1.0000x reference)
//
#include <hip/hip_runtime.h>

// Fold / col2im: B=16, C=64, K=3, H=W=128, PAD=1, STR=DIL=1, LH=LW=128.
// Gather formulation: out[b,c,h,w] = sum_{a,bk} x[b, c*9 + a*3+bk, (h+1-a)*128 + (w+1-bk)]
// valid when 0 <= h+1-a < 128 and 0 <= w+1-bk < 128.

#define FOLD_B   16
#define FOLD_C   64
#define FOLD_H   128
#define FOLD_W   128
#define FOLD_L   (128 * 128)        // LH*LW plane size
#define FOLD_N   (FOLD_B * FOLD_C * FOLD_H * FOLD_W)   // 16,777,216 outputs

__global__ __launch_bounds__(256) void fold_gather_kernel(
    const float* __restrict__ x, float* __restrict__ out)
{
    int idx = blockIdx.x * blockDim.x + threadIdx.x;
    if (idx >= FOLD_N) return;

    int w = idx & 127;
    int h = (idx >> 7) & 127;
    int c = (idx >> 14) & 63;
    int b = idx >> 20;

    int r = h + 1;   // padded row
    int s = w + 1;   // padded col

    // base of the 9 planes for (b, c): plane p = c*9 + a*3 + bk, plane stride = 16384
    const float* base = x + ((size_t)(b * (FOLD_C * 9) + c * 9)) * FOLD_L;

    float acc = 0.0f;
#pragma unroll
    for (int a = 0; a < 3; ++a) {
        int i = r - a;
        if ((unsigned)i < 128u) {
            const float* row = base + a * 3 * FOLD_L + i * 128;
#pragma unroll
            for (int bk = 0; bk < 3; ++bk) {
                int j = s - bk;
                if ((unsigned)j < 128u) {
                    acc += row[bk * FOLD_L + j];
                }
            }
        }
    }
    out[idx] = acc;
}

extern "C" void kernel_launch(void* const* d_in, const int* in_sizes, int n_in,
                              void* d_out, int out_size, void* d_ws, size_t ws_size,
                              hipStream_t stream)
{
    const float* x = (const float*)d_in[0];
    float* out = (float*)d_out;

    const int threads = 256;
    const int blocks = (FOLD_N + threads - 1) / threads;   // 65536
    fold_gather_kernel<<<blocks, threads, 0, stream>>>(x, out);
}

// Round 2
// 758.827 us; speedup vs baseline: 1.0654x; 1.0654x over previous
//
#include <hip/hip_runtime.h>

// Fold / col2im: B=16, C=64, K=3, H=W=128, PAD=1, STR=DIL=1, LH=LW=128.
// Gather: out[b,c,h,w] = sum_{a,bk} P[b, c*9+a*3+bk, h+1-a, w+1-bk]  (valid idx only)
// Vectorized: one float4 of output per thread; one aligned dwordx4 load per plane;
// +-1 column shifts via lane shuffles; row-boundary masking coincides with the
// wave positions where the shuffle would cross rows.

typedef float float4v __attribute__((ext_vector_type(4)));

#define FOLD_L      16384          // plane size LH*LW (floats)
#define FOLD_NT     (16 * 64 * 128 * 32)   // 4,194,304 threads (float4 each)

__global__ __launch_bounds__(256) void fold_gather_v4_kernel(
    const float* __restrict__ x, float* __restrict__ out)
{
    int tid = blockIdx.x * blockDim.x + threadIdx.x;

    int w4 = tid & 31;            // which float4 within the 128-wide row
    int h  = (tid >> 5) & 127;
    int bc = tid >> 12;           // b*64 + c  (0..1023)

    const float* base = x + (size_t)bc * 9 * FOLD_L;
    int w0 = w4 << 2;

    bool first = (w4 == 0);
    bool last  = (w4 == 31);

    float4v acc = {0.f, 0.f, 0.f, 0.f};

#pragma unroll
    for (int a = 0; a < 3; ++a) {
        int i = h + 1 - a;
        bool va = ((unsigned)i < 128u);
        int ic = va ? i : 0;                       // clamp; contribution zeroed below
        const float* rb = base + (size_t)(a * 3) * FOLD_L + ic * 128 + w0;

        float4v v0 = *(const float4v*)(rb);                 // bk=0 plane (j = w+1)
        float4v v1 = *(const float4v*)(rb + FOLD_L);        // bk=1 plane (j = w)
        float4v v2 = *(const float4v*)(rb + 2 * FOLD_L);    // bk=2 plane (j = w-1)

        float nxt = __shfl_down(v0.x, 1);   // next lane's first elem (col w0+4) of bk=0
        float prv = __shfl_up(v2.w, 1);     // prev lane's last  elem (col w0-1) of bk=2

        float4v s;
        s.x = v0.y + v1.x + (first ? 0.0f : prv);
        s.y = v0.z + v1.y + v2.x;
        s.z = v0.w + v1.z + v2.y;
        s.w = (last ? 0.0f : nxt) + v1.w + v2.z;

        float m = va ? 1.0f : 0.0f;
        acc += m * s;
    }

    ((float4v*)out)[tid] = acc;
}

extern "C" void kernel_launch(void* const* d_in, const int* in_sizes, int n_in,
                              void* d_out, int out_size, void* d_ws, size_t ws_size,
                              hipStream_t stream)
{
    const float* x = (const float*)d_in[0];
    float* out = (float*)d_out;

    const int threads = 256;
    const int blocks = FOLD_NT / threads;   // 16384
    fold_gather_v4_kernel<<<blocks, threads, 0, stream>>>(x, out);
}